// Round 19
// baseline (72.845 us; speedup 1.0000x reference)
//
#include <hip/hip_runtime.h>

// Separable 3D Gaussian blur (sigma=1, truncate=3 -> 7 taps), SAME zero padding.
// (N=2, D=160, H=160, W=160, C=4) float32 == float4 over C.
// Round 19 = R18 (zero-barrier wave-autonomous, 70.4us) with 1-WAVE BLOCKS:
//   64-thread blocks, one 16x16 tile per block. LDS per block 14.1 KB ->
//   scheduler packs floor(160/14.1) = 11 waves/CU vs R18's 8 (4-wave blocks
//   quantized to 2x56.3KB). +37% TLP against the same per-CU LDS/VALU work.
// All else identical to R18: private raw[22][23]+wb[22][17] f4 tiles, no
// s_barrier (intra-wave lgkmcnt ordering only), register prefetch 1 slice
// ahead, 4 D-rings/lane (4 output rows), CHUNK=16, bijective XCD swizzle
// (2000 = 8 x 250 exact).

#define THT 16
#define TWT 16
#define CHUNK 16
#define NS (CHUNK + 6)      // 22 slices per wave
#define DIM 160
#define SLICE (DIM * DIM)
#define HALON (22 * 22)     // 484 staged f4 per slice
#define NBLK 2000           // 2n x 10th x 10tw x 10chunk, = 8 XCDs x 250

#define W0 0.004433048f
#define W1 0.054005582f
#define W2 0.242036229f
#define W3 0.399050300f

__device__ __forceinline__ float4 blur7(float4 a0, float4 a1, float4 a2, float4 a3,
                                        float4 a4, float4 a5, float4 a6) {
    float4 r;
    r.x = W0 * (a0.x + a6.x) + W1 * (a1.x + a5.x) + W2 * (a2.x + a4.x) + W3 * a3.x;
    r.y = W0 * (a0.y + a6.y) + W1 * (a1.y + a5.y) + W2 * (a2.y + a4.y) + W3 * a3.y;
    r.z = W0 * (a0.z + a6.z) + W1 * (a1.z + a5.z) + W2 * (a2.z + a4.z) + W3 * a3.z;
    r.w = W0 * (a0.w + a6.w) + W1 * (a1.w + a5.w) + W2 * (a2.w + a4.w) + W3 * a3.w;
    return r;
}

__global__ __launch_bounds__(64, 2)
void gauss3d_fused(const float4* __restrict__ in, float4* __restrict__ out) {
    // bijective XCD-chunked swizzle: 2000 = 8 * 250 exactly.
    const int bid = blockIdx.x;
    int wid = (bid & 7) * (NBLK / 8) + (bid >> 3);

    const int lane = threadIdx.x;   // 0..63

    const int tw    = wid % 10;  wid /= 10;
    const int th    = wid % 10;  wid /= 10;
    const int chunk = wid % 10;  wid /= 10;
    const int n     = wid;          // 0..1

    const int h0 = th * THT;
    const int w0 = tw * TWT;
    const int d0 = chunk * CHUNK;

    __shared__ float4 raw[22][23];   // halo tile, +1 col pad (14.1 KB total)
    __shared__ float4 wb[22][17];    // W-blurred tile, +1 col pad

    const size_t nbase = (size_t)n * DIM * SLICE;
    const float4 z = make_float4(0.f, 0.f, 0.f, 0.f);

    // ---- stage constants: 484 halo f4 over 64 lanes (8 slots) ----
    int  soff[8], ridx[8];
    bool sok[8];
    #pragma unroll
    for (int s = 0; s < 8; ++s) {
        const int j = lane + 64 * s;
        const bool has = (j < HALON);
        const int rr = has ? (j / 22) : 0, cc = has ? (j % 22) : 0;
        const int gh = h0 + rr - 3, gw = w0 + cc - 3;
        const bool ok = has && gh >= 0 && gh < DIM && gw >= 0 && gw < DIM;
        soff[s] = ok ? (gh * DIM + gw) : 0;
        sok[s]  = ok;
        ridx[s] = rr * 23 + cc;
    }
    const bool has7 = (lane + 448 < HALON);   // lane < 36

    // ---- W-blur groups: 88 groups of 4 outputs; lane does g=lane and
    //      (lane<24) g=64+lane ----
    const int g1r = lane >> 2, g1c = (lane & 3) * 4;
    const bool hasG2 = (lane < 24);
    const int g2r = (64 + lane) >> 2, g2c = ((64 + lane) & 3) * 4;

    // ---- H-blur: q = lane>>4 -> rows 4q..4q+3, lw = lane&15 ----
    const int q  = lane >> 4;
    const int lw = lane & 15;

    // 4 D-rings (output rows 4q..4q+3), 7 deep each
    float4 qa0=z,qa1=z,qa2=z,qa3=z,qa4=z,qa5=z,qa6=z;
    float4 qb0=z,qb1=z,qb2=z,qb3=z,qb4=z,qb5=z,qb6=z;
    float4 qc0=z,qc1=z,qc2=z,qc3=z,qc4=z,qc5=z,qc6=z;
    float4 qd0=z,qd1=z,qd2=z,qd3=z,qd4=z,qd5=z,qd6=z;

    float4 pf0, pf1, pf2, pf3, pf4, pf5, pf6, pf7;

#define PREFETCH(DSL)                                                        \
    do {                                                                     \
        const int _d = (DSL);                                                \
        const bool _inr = (_d >= 0) && (_d < DIM);                           \
        const float4* _s = in + nbase + (size_t)(_inr ? _d : 0) * SLICE;     \
        pf0 = (_inr && sok[0]) ? _s[soff[0]] : z;                            \
        pf1 = (_inr && sok[1]) ? _s[soff[1]] : z;                            \
        pf2 = (_inr && sok[2]) ? _s[soff[2]] : z;                            \
        pf3 = (_inr && sok[3]) ? _s[soff[3]] : z;                            \
        pf4 = (_inr && sok[4]) ? _s[soff[4]] : z;                            \
        pf5 = (_inr && sok[5]) ? _s[soff[5]] : z;                            \
        pf6 = (_inr && sok[6]) ? _s[soff[6]] : z;                            \
        pf7 = (_inr && sok[7]) ? _s[soff[7]] : z;                            \
    } while (0)

#define WGRP(R, C0)                                                          \
    do {                                                                     \
        const float4* _rr = &raw[R][0];                                      \
        float4 v0 = _rr[(C0) + 0];                                           \
        float4 v1 = _rr[(C0) + 1];                                           \
        float4 v2 = _rr[(C0) + 2];                                           \
        float4 v3 = _rr[(C0) + 3];                                           \
        float4 v4 = _rr[(C0) + 4];                                           \
        float4 v5 = _rr[(C0) + 5];                                           \
        float4 v6 = _rr[(C0) + 6];                                           \
        float4 v7 = _rr[(C0) + 7];                                           \
        float4 v8 = _rr[(C0) + 8];                                           \
        float4 v9 = _rr[(C0) + 9];                                           \
        float4* _wr = &wb[R][0];                                             \
        _wr[(C0) + 0] = blur7(v0, v1, v2, v3, v4, v5, v6);                   \
        _wr[(C0) + 1] = blur7(v1, v2, v3, v4, v5, v6, v7);                   \
        _wr[(C0) + 2] = blur7(v2, v3, v4, v5, v6, v7, v8);                   \
        _wr[(C0) + 3] = blur7(v3, v4, v5, v6, v7, v8, v9);                   \
    } while (0)

    PREFETCH(d0 - 3);

    for (int k = 0; k < NS; ++k) {
        const int din = d0 - 3 + k;

        // 1) commit prefetched slice into raw
        {
            float4* rb = &raw[0][0];
            rb[ridx[0]] = pf0;
            rb[ridx[1]] = pf1;
            rb[ridx[2]] = pf2;
            rb[ridx[3]] = pf3;
            rb[ridx[4]] = pf4;
            rb[ridx[5]] = pf5;
            rb[ridx[6]] = pf6;
            if (has7) rb[ridx[7]] = pf7;
        }

        // 2) issue next slice's loads (latency hides under W+H phases)
        if (k + 1 < NS) PREFETCH(din + 1);

        // 3) W-blur (intra-wave lgkmcnt orders raw writes -> reads)
        WGRP(g1r, g1c);
        if (hasG2) WGRP(g2r, g2c);

        // 4) H-blur: 10 wb reads -> 4 new ring values (rows 4q..4q+3)
        {
            float4 t0 = wb[4 * q + 0][lw];
            float4 t1 = wb[4 * q + 1][lw];
            float4 t2 = wb[4 * q + 2][lw];
            float4 t3 = wb[4 * q + 3][lw];
            float4 t4 = wb[4 * q + 4][lw];
            float4 t5 = wb[4 * q + 5][lw];
            float4 t6 = wb[4 * q + 6][lw];
            float4 t7 = wb[4 * q + 7][lw];
            float4 t8 = wb[4 * q + 8][lw];
            float4 t9 = wb[4 * q + 9][lw];
            float4 va = blur7(t0, t1, t2, t3, t4, t5, t6);
            float4 vb = blur7(t1, t2, t3, t4, t5, t6, t7);
            float4 vc = blur7(t2, t3, t4, t5, t6, t7, t8);
            float4 vd = blur7(t3, t4, t5, t6, t7, t8, t9);
            qa0=qa1; qa1=qa2; qa2=qa3; qa3=qa4; qa4=qa5; qa5=qa6; qa6=va;
            qb0=qb1; qb1=qb2; qb2=qb3; qb3=qb4; qb4=qb5; qb5=qb6; qb6=vb;
            qc0=qc1; qc1=qc2; qc2=qc3; qc3=qc4; qc4=qc5; qc5=qc6; qc6=vc;
            qd0=qd1; qd1=qd2; qd2=qd3; qd3=qd4; qd4=qd5; qd5=qd6; qd6=vd;
        }

        // 5) emit 4 output rows for dout = din-3 once rings are primed
        if (k >= 6) {
            const int dout = din - 3;
            float4 oa = blur7(qa0, qa1, qa2, qa3, qa4, qa5, qa6);
            float4 ob = blur7(qb0, qb1, qb2, qb3, qb4, qb5, qb6);
            float4 oc = blur7(qc0, qc1, qc2, qc3, qc4, qc5, qc6);
            float4 od = blur7(qd0, qd1, qd2, qd3, qd4, qd5, qd6);
            const size_t base = nbase + (size_t)dout * SLICE + (size_t)(h0 + 4 * q) * DIM + (w0 + lw);
            out[base + 0 * DIM] = oa;
            out[base + 1 * DIM] = ob;
            out[base + 2 * DIM] = oc;
            out[base + 3 * DIM] = od;
        }
    }
#undef PREFETCH
#undef WGRP
}

extern "C" void kernel_launch(void* const* d_in, const int* in_sizes, int n_in,
                              void* d_out, int out_size, void* d_ws, size_t ws_size,
                              hipStream_t stream) {
    const float4* in = (const float4*)d_in[0];
    float4* out = (float4*)d_out;
    gauss3d_fused<<<NBLK, 64, 0, stream>>>(in, out);
}